// Round 1
// baseline (3419.441 us; speedup 1.0000x reference)
//
#include <hip/hip_runtime.h>

#define VOCAB   4096
#define HIDDEN  512
#define BATCH   64
#define TSTEPS  512
#define NWG     32      // workgroups in the RNN scan (16 hidden cols each)

typedef short bf16x8 __attribute__((ext_vector_type(8)));   // 8 bf16 = 4 VGPRs (guide §3)
typedef float f32x4  __attribute__((ext_vector_type(4)));

// fp32 -> bf16 round-to-nearest-even (values are finite; no NaN path needed)
__device__ __forceinline__ unsigned short f2bf(float f) {
  unsigned int x = __float_as_uint(f);
  unsigned int r = (x + 0x7fffu + ((x >> 16) & 1u)) >> 16;
  return (unsigned short)r;
}

// async global->LDS, 16B per lane. LDS side is wave-uniform base + lane*16;
// global side is per-lane (scatter allowed).
__device__ __forceinline__ void async16(const void* g, void* l) {
  __builtin_amdgcn_global_load_lds(
      (const __attribute__((address_space(1))) unsigned int*)g,
      (__attribute__((address_space(3))) unsigned int*)l, 16, 0, 0);
}

// ---------------------------------------------------------------------------
// prep_small: convert initial hidden (fp32, zeros in practice) to bf16 hbuf[0]
// and zero the 512 per-step barrier counters (ws is poisoned 0xAA each launch).
// grid 128 x 256 = 32768 threads exactly.
__global__ void prep_small(const float* __restrict__ hidden,
                           unsigned short* __restrict__ hbuf,
                           int* __restrict__ bar) {
  int i = blockIdx.x * 256 + threadIdx.x;
  hbuf[i] = f2bf(hidden[i]);
  if (i < TSTEPS) bar[i] = 0;
}

// ---------------------------------------------------------------------------
// build_Wb: Wb[v][h] = W_ih[h][v] + b_ih[h] + b_hh[h]   (fp32, 4096x512)
// 64x64 LDS tile transpose. grid 512 (64 v-tiles x 8 h-tiles), block 256.
__global__ void build_Wb(const float* __restrict__ W_ih,
                         const float* __restrict__ b_ih,
                         const float* __restrict__ b_hh,
                         float* __restrict__ Wb) {
  __shared__ float t[64][65];
  int bx = blockIdx.x;
  int vt = bx & 63, ht = bx >> 6;
  int v0 = vt * 64, h0 = ht * 64;
  int tx = threadIdx.x & 15, ty = threadIdx.x >> 4;
#pragma unroll
  for (int a = 0; a < 4; ++a) {
    int h = h0 + ty + 16 * a;
    float4 v = *(const float4*)&W_ih[(size_t)h * VOCAB + v0 + tx * 4];
    t[ty + 16 * a][tx * 4 + 0] = v.x;
    t[ty + 16 * a][tx * 4 + 1] = v.y;
    t[ty + 16 * a][tx * 4 + 2] = v.z;
    t[ty + 16 * a][tx * 4 + 3] = v.w;
  }
  __syncthreads();
#pragma unroll
  for (int a = 0; a < 4; ++a) {
    int v = v0 + ty + 16 * a;
    int hh = h0 + tx * 4;
    float4 o;
    o.x = t[tx * 4 + 0][ty + 16 * a] + b_ih[hh + 0] + b_hh[hh + 0];
    o.y = t[tx * 4 + 1][ty + 16 * a] + b_ih[hh + 1] + b_hh[hh + 1];
    o.z = t[tx * 4 + 2][ty + 16 * a] + b_ih[hh + 2] + b_hh[hh + 2];
    o.w = t[tx * 4 + 3][ty + 16 * a] + b_ih[hh + 3] + b_hh[hh + 3];
    *(float4*)&Wb[(size_t)v * HIDDEN + hh] = o;
  }
}

// ---------------------------------------------------------------------------
// conv_wfc: W_fc fp32 -> bf16. 2097152 elems, 4/thread, grid 2048 x 256 exact.
__global__ void conv_wfc(const float* __restrict__ W, unsigned short* __restrict__ o) {
  int i = (blockIdx.x * 256 + threadIdx.x) * 4;
  float4 v = *(const float4*)&W[i];
  ushort4 u;
  u.x = f2bf(v.x); u.y = f2bf(v.y); u.z = f2bf(v.z); u.w = f2bf(v.w);
  *(ushort4*)&o[i] = u;
}

// ---------------------------------------------------------------------------
// rnn_scan: 32 WGs x 256 threads. WG w owns hidden cols [16w,16w+16).
// W_hh slice lives in registers as MFMA B-fragments for the whole kernel.
// Per step: device barrier (per-step counter, release/acquire agent scope),
// stage h_{t} (bf16, 64KB) -> LDS via global_load_lds with per-row rotation,
// 16 MFMAs per wave (wave = m-tile of 16 batches), tanh epilogue, store
// h_{t+1} slice + out_h slice.
__global__ __launch_bounds__(256) void rnn_scan(
    const float* __restrict__ Whh,      // [512][512] fp32
    const float* __restrict__ Wb,       // [4096][512] fp32 (biases folded)
    const int* __restrict__ inp,        // [64][512]
    unsigned short* __restrict__ hbuf,  // [2][64][512] bf16
    unsigned short* __restrict__ outH,  // [32768][512] bf16  (row = b*T + t)
    float* __restrict__ hlast,          // [64][512] fp32 (d_out tail)
    int* __restrict__ bar) {            // [512] arrival counters (pre-zeroed)
  __shared__ unsigned short lh[BATCH * HIDDEN];  // 64KB, rotated rows

  const int tid  = threadIdx.x;
  const int wg   = blockIdx.x;
  const int wave = tid >> 6, lane = tid & 63;
  const int quad = lane >> 4, lrow = lane & 15;
  const int n0   = wg * 16;

  // B-frags: lane holds Whh[n0+lrow][kc*32 + quad*8 + j], j=0..7 (bf16)
  bf16x8 bfrag[16];
  {
    const float* wsrc = Whh + (size_t)(n0 + lrow) * HIDDEN + quad * 8;
#pragma unroll
    for (int kc = 0; kc < 16; ++kc) {
      float4 f0 = *(const float4*)(wsrc + kc * 32);
      float4 f1 = *(const float4*)(wsrc + kc * 32 + 4);
      bf16x8 v;
      v[0] = (short)f2bf(f0.x); v[1] = (short)f2bf(f0.y);
      v[2] = (short)f2bf(f0.z); v[3] = (short)f2bf(f0.w);
      v[4] = (short)f2bf(f1.x); v[5] = (short)f2bf(f1.y);
      v[6] = (short)f2bf(f1.z); v[7] = (short)f2bf(f1.w);
      bfrag[kc] = v;
    }
  }

  const int m   = wave * 16 + lrow;                    // A-frag row (batch)
  const int rot = (HIDDEN - 8 * m) & (HIDDEN - 1);     // undo staging rotation

  for (int t = 0; t < TSTEPS; ++t) {
    if (t > 0) {
      if (tid == 0) {
        int lim = 1 << 21;  // bounded spin: fail loud (wrong data), not hang
        while (__hip_atomic_load(&bar[t - 1], __ATOMIC_ACQUIRE,
                                 __HIP_MEMORY_SCOPE_AGENT) < NWG && --lim) {}
      }
      __syncthreads();
    }

    // stage h_t -> LDS. wave stages its own 16 rows; row r rotated by 8r elems
    // so b128 frag reads hit the optimal 8-accesses/bank pattern.
    const unsigned short* hsrc = hbuf + (size_t)(t & 1) * (BATCH * HIDDEN);
#pragma unroll
    for (int rr = 0; rr < 16; ++rr) {
      int row = wave * 16 + rr;
      const unsigned short* g = hsrc + (size_t)row * HIDDEN +
                                (((unsigned)(lane * 8 + row * 8)) & (HIDDEN - 1));
      async16(g, &lh[row * HIDDEN]);
    }
    __syncthreads();  // drains vmcnt -> LDS-DMA complete

    f32x4 acc = {0.f, 0.f, 0.f, 0.f};
#pragma unroll
    for (int kc = 0; kc < 16; ++kc) {
      int k = kc * 32 + quad * 8;
      int p = (k + rot) & (HIDDEN - 1);
      bf16x8 af = *(const bf16x8*)&lh[m * HIDDEN + p];
      acc = __builtin_amdgcn_mfma_f32_16x16x32_bf16(af, bfrag[kc], acc, 0, 0, 0);
    }

    // epilogue: C/D layout col=lane&15 (n), row=quad*4+r (b within m-tile)
    unsigned short* hdst = hbuf + (size_t)((t + 1) & 1) * (BATCH * HIDDEN);
#pragma unroll
    for (int r = 0; r < 4; ++r) {
      int b   = wave * 16 + quad * 4 + r;
      int idx = inp[b * TSTEPS + t];
      float x = Wb[(size_t)idx * HIDDEN + n0 + lrow];
      float hv = tanhf(x + acc[r]);
      unsigned short hb = f2bf(hv);
      hdst[b * HIDDEN + n0 + lrow] = hb;
      outH[(size_t)(b * TSTEPS + t) * HIDDEN + n0 + lrow] = hb;
      if (t == TSTEPS - 1) hlast[b * HIDDEN + n0 + lrow] = hv;
    }

    __syncthreads();  // all waves' stores drained (vmcnt(0) before s_barrier)
    if (tid == 0) {
      // release at agent scope: writes back L2 so other XCDs see h_{t+1}
      __hip_atomic_fetch_add(&bar[t], 1, __ATOMIC_RELEASE,
                             __HIP_MEMORY_SCOPE_AGENT);
    }
  }
}

// ---------------------------------------------------------------------------
// logits_gemm: C[32768][4096] fp32 = A[32768][512]bf16 * B[4096][512]bf16^T + bias
// 128x128 tile, BK=64, global_load_lds width 16, 4 waves x (4x4 16x16 tiles).
__global__ __launch_bounds__(256) void logits_gemm(
    const unsigned short* __restrict__ A,     // outH
    const unsigned short* __restrict__ B,     // W_fc bf16
    const float* __restrict__ bias,           // b_fc
    float* __restrict__ C) {
  __shared__ unsigned short lA[128 * 64];
  __shared__ unsigned short lB[128 * 64];

  const int tid  = threadIdx.x;
  const int wave = tid >> 6, lane = tid & 63;
  const int quad = lane >> 4, lrow = lane & 15;
  const int bx = blockIdx.x;
  const int m0 = (bx >> 5) * 128;   // 256 m-tiles
  const int n0 = (bx & 31) * 128;   // 32 n-tiles
  const int wm = wave & 1, wn = wave >> 1;
  const int lr8 = (lane & 7) * 8;   // k offset within staged chunk
  const int lrw = lane >> 3;        // row within 8-row stage group

  f32x4 acc[4][4];
#pragma unroll
  for (int i = 0; i < 4; ++i)
#pragma unroll
    for (int j = 0; j < 4; ++j) acc[i][j] = (f32x4){0.f, 0.f, 0.f, 0.f};

  for (int kk = 0; kk < 8; ++kk) {
    __syncthreads();
    const int kb = kk * 64;
#pragma unroll
    for (int s = 0; s < 4; ++s) {
      int rA = wave * 32 + s * 8;   // 8 rows per instr, 32 rows per wave
      async16(A + (size_t)(m0 + rA + lrw) * HIDDEN + kb + lr8, &lA[rA * 64]);
      async16(B + (size_t)(n0 + rA + lrw) * HIDDEN + kb + lr8, &lB[rA * 64]);
    }
    __syncthreads();
#pragma unroll
    for (int kc = 0; kc < 2; ++kc) {
      bf16x8 af[4], bq[4];
#pragma unroll
      for (int i = 0; i < 4; ++i) {
        af[i] = *(const bf16x8*)&lA[(wm * 64 + i * 16 + lrow) * 64 + kc * 32 + quad * 8];
        bq[i] = *(const bf16x8*)&lB[(wn * 64 + i * 16 + lrow) * 64 + kc * 32 + quad * 8];
      }
#pragma unroll
      for (int i = 0; i < 4; ++i)
#pragma unroll
        for (int j = 0; j < 4; ++j)
          acc[i][j] = __builtin_amdgcn_mfma_f32_16x16x32_bf16(af[i], bq[j], acc[i][j], 0, 0, 0);
    }
  }

#pragma unroll
  for (int i = 0; i < 4; ++i) {
    int row = m0 + wm * 64 + i * 16 + quad * 4;
#pragma unroll
    for (int j = 0; j < 4; ++j) {
      int col = n0 + wn * 64 + j * 16 + lrow;
      float bs = bias[col];
#pragma unroll
      for (int r = 0; r < 4; ++r)
        C[(size_t)(row + r) * VOCAB + col] = acc[i][j][r] + bs;
    }
  }
}

// ---------------------------------------------------------------------------
extern "C" void kernel_launch(void* const* d_in, const int* in_sizes, int n_in,
                              void* d_out, int out_size, void* d_ws, size_t ws_size,
                              hipStream_t stream) {
  const int*   inp    = (const int*)d_in[0];
  const float* hidden = (const float*)d_in[1];
  const float* W_ih   = (const float*)d_in[2];
  const float* W_hh   = (const float*)d_in[3];
  const float* b_ih   = (const float*)d_in[4];
  const float* b_hh   = (const float*)d_in[5];
  const float* W_fc   = (const float*)d_in[6];
  const float* b_fc   = (const float*)d_in[7];

  char* ws = (char*)d_ws;
  float*          Wb   = (float*)ws;                                  // 8 MB
  unsigned short* Wfcb = (unsigned short*)(ws + (8  << 20));          // 4 MB
  unsigned short* outH = (unsigned short*)(ws + (12 << 20));          // 32 MB
  unsigned short* hbuf = (unsigned short*)(ws + (44 << 20));          // 128 KB
  int*            bar  = (int*)(ws + (44 << 20) + (1 << 18));         // 2 KB

  float* logits = (float*)d_out;                                      // [B,T,V]
  float* hlast  = logits + (size_t)BATCH * TSTEPS * VOCAB;            // [1,B,H]

  prep_small<<<128, 256, 0, stream>>>(hidden, hbuf, bar);
  build_Wb<<<512, 256, 0, stream>>>(W_ih, b_ih, b_hh, Wb);
  conv_wfc<<<2048, 256, 0, stream>>>(W_fc, Wfcb);
  rnn_scan<<<NWG, 256, 0, stream>>>(W_hh, Wb, inp, hbuf, outH, hlast, bar);
  logits_gemm<<<8192, 256, 0, stream>>>(outH, Wfcb, b_fc, logits);
}